// Round 8
// baseline (369.190 us; speedup 1.0000x reference)
//
#include <hip/hip_runtime.h>
#include <hip/hip_bf16.h>
#include <cstdint>

// DifferentiableILP on MI355X (gfx950).
// A = softmax(rule_weights[:,0,:]); 3x: facts = max(facts, colmax(A @ facts)).
// Columns independent -> each block owns a 128-col stripe; ft immutable in LDS,
// running col-max folded into B fragments at use (packed u16 max).
//
// R10 changes vs R9 (ilp 156us, MfmaUtil 28.3%, feeds <=75% ceilings):
//  - Diagnosis: 9 configs, all 144-160us; k-step wall ~700cy vs 256cy pipe.
//    The invariant: 2-deep buffers force vmcnt(2)/lgkmcnt(4) before EVERY
//    cluster; s_waitcnt drain costs 156-332cy even L2-warm (m135). Every
//    step paid a drain no structural change touched.
//  - 3-deep rotation (slot k%3), prefetch k+2 issued BEFORE the cluster
//    (no WAR: different slot). Steady-state waits become vmcnt(4)/lgkmcnt(8)
//    = no-ops (exactly 4 A + 8 B outstanding). k-loop fully unrolled ->
//    static slots, immediate ds offsets.
//  - In-loop pkmax fold restored (R4 149.8 w/ fold < R8 160 w/o): deletes
//    update pass + 1 barrier + B reloads; ft immutable again.
//  - s_setprio removed (m190: measured negative on non-phase-split GEMM).
//  - Seam: prefetch capped at kt2<30; A/B slots 0,1 reloaded at iteration
//    boundary (hidden under the reduce barrier). 32%3!=0 makes the rotation
//    phase iteration-variant otherwise.

typedef __attribute__((ext_vector_type(8))) short bf16x8;   // 8 bf16 = 4 VGPRs
typedef __attribute__((ext_vector_type(8))) unsigned short u16x8;
typedef __attribute__((ext_vector_type(16))) float f32x16;  // 32x32 accumulator
typedef unsigned short ushort_t;
typedef unsigned int uint32;

#define PDIM 512
#define CDIM 65536
#define NT   128     // columns per block
#define WAVES 8

__device__ __forceinline__ ushort_t f2bf(float x) {          // RNE float->bf16
    uint32 u = __float_as_uint(x);
    return (ushort_t)((u + 0x7fffu + ((u >> 16) & 1u)) >> 16);
}
__device__ __forceinline__ float bf2f(uint32 bits) { return __uint_as_float(bits << 16); }

// packed max(v, splat(mu)) in the u16 domain (valid: all values are nonneg bf16)
__device__ __forceinline__ bf16x8 pkmax8(bf16x8 v, ushort_t mu) {
    u16x8 a = __builtin_bit_cast(u16x8, v);
    const u16x8 mb = {mu, mu, mu, mu, mu, mu, mu, mu};
    a = __builtin_elementwise_max(a, mb);
    return __builtin_bit_cast(bf16x8, a);
}

// ---- phase 1: softmax row r, packed fragment-linear for 32x32x16 MFMA.
// chunk idx16 = (kt2*16 + (r>>5))*64 + (ln&1)*32 + (r&31) holds
// A[r][kt2*16 + (ln&1)*8 .. +7] as 8 bf16.  (unchanged since R5)
__global__ __launch_bounds__(64) void softmax_pack(const float* __restrict__ rw,
                                                   ushort_t* __restrict__ Apk) {
    const int r  = blockIdx.x;
    const int ln = threadIdx.x;
    const float* row = rw + r * PDIM;
    float4 x0 = *(const float4*)(row + ln * 8);
    float4 x1 = *(const float4*)(row + ln * 8 + 4);
    float v[8] = {x0.x, x0.y, x0.z, x0.w, x1.x, x1.y, x1.z, x1.w};

    float mx = -1e30f;
    #pragma unroll
    for (int i = 0; i < 8; ++i) mx = fmaxf(mx, v[i]);
    #pragma unroll
    for (int d = 1; d < 64; d <<= 1) mx = fmaxf(mx, __shfl_xor(mx, d, 64));
    float s = 0.f;
    #pragma unroll
    for (int i = 0; i < 8; ++i) { v[i] = __expf(v[i] - mx); s += v[i]; }
    #pragma unroll
    for (int d = 1; d < 64; d <<= 1) s += __shfl_xor(s, d, 64);
    const float inv = 1.f / s;

    ushort_t o[8];
    #pragma unroll
    for (int i = 0; i < 8; ++i) o[i] = f2bf(v[i] * inv);
    const int idx16 = ((ln >> 1) * 16 + (r >> 5)) * 64 + ((ln & 1) << 5) + (r & 31);
    *(int4*)(Apk + idx16 * 8) = *(const int4*)o;
}

// ---- phase 2: per-128-column stripe, fused multi-iteration fixpoint.
// LDS ftB: 16B chunk (g, c) at element (g*NT + c)*8, g = p-granule (p=g*8..+7).
__global__ __launch_bounds__(512, 2) void ilp_kernel(
        const float* __restrict__ facts,
        const ushort_t* __restrict__ Apk,
        const int* __restrict__ n_iter_p,
        float* __restrict__ out) {
    __shared__ ushort_t ft[64 * NT * 8];   // 131072 B
    __shared__ float wred[2][WAVES][NT];   // 8192 B: per-wave colmax partials, dbuf

    const int tid  = threadIdx.x;
    const int wave = tid >> 6;
    const int lane = tid & 63;
    const int l31  = lane & 31;
    const int half = lane >> 5;
    const int c0   = blockIdx.x * NT;

    int n_iter = *n_iter_p;                // issue scalar load early
    n_iter = n_iter < 0 ? 0 : (n_iter > 8 ? 8 : n_iter);

    wred[0][wave][lane]      = 0.f;        // n_iter==0 safety
    wred[0][wave][lane + 64] = 0.f;

    // ---- stage: ftB[g][c] = bf16(facts[g*8..+7][c0+c]); 1 col/lane.
    // Global: 256B/wave-instr coalesced. LDS: 16 consecutive lanes span 256B
    // contiguous -> conflict-free b128 writes.
    {
        const int c   = tid & 127;
        const int grp = tid >> 7;          // 0..3
        #pragma unroll 4
        for (int s = 0; s < 16; ++s) {
            const int g = grp * 16 + s;
            ushort_t gb[8];
            #pragma unroll
            for (int i = 0; i < 8; ++i)
                gb[i] = f2bf(facts[(g * 8 + i) * CDIM + c0 + c]);
            *(int4*)(&ft[(g * NT + c) * 8]) = *(const int4*)gb;
        }
    }

    // A prologue (kt2=0,1 -> slots 0,1) issued before the barrier.
    // wave owns rows wave*64 + rt2*32 + l31;
    // element = wave*1024 + rt2*512 + (half*32+l31)*8 + kt2*8192.
    const ushort_t* abase = Apk + wave * 1024 + (half * 32 + l31) * 8;
    bf16x8 aF[3][2], bR[3][4];
    #pragma unroll
    for (int s = 0; s < 2; ++s) {
        aF[s][0] = *(const bf16x8*)(abase + s * 8192);
        aF[s][1] = *(const bf16x8*)(abase + s * 8192 + 512);
    }

    __syncthreads();

    // B element base: ((kt2*2+half)*NT + ct2*32 + l31)*8 = bbase + kt2*2048 + ct2*256
    const int bbase = (half * NT + l31) * 8;
    #pragma unroll
    for (int s = 0; s < 2; ++s)
        #pragma unroll
        for (int ct2 = 0; ct2 < 4; ++ct2)
            bR[s][ct2] = *(const bf16x8*)(&ft[bbase + s * 2048 + ct2 * 256]);

    ushort_t ml[4] = {0, 0, 0, 0};         // running colmax, bf16 bits
    float    mf[4] = {0.f, 0.f, 0.f, 0.f}; // running colmax, f32

    #pragma unroll 1
    for (int it = 0; it < n_iter; ++it) {
        f32x16 acc[2][4];
        #pragma unroll
        for (int rt2 = 0; rt2 < 2; ++rt2)
            #pragma unroll
            for (int ct2 = 0; ct2 < 4; ++ct2)
                #pragma unroll
                for (int e = 0; e < 16; ++e) acc[rt2][ct2][e] = 0.f;

        // ---- k-loop, fully unrolled: static 3-slot rotation. Prefetch for
        // k+2 issued BEFORE the cluster (different slot -> no WAR); steady-
        // state waits are vmcnt(4)/lgkmcnt(8) = no-ops.
        #pragma unroll
        for (int kt2 = 0; kt2 < 32; ++kt2) {
            const int cur = kt2 % 3;

            if (kt2 < 30) {
                const int nxt = (kt2 + 2) % 3;
                {   // B prefetch k+2 (4x ds_read_b128, conflict-free)
                    const int bo = bbase + (kt2 + 2) * 2048;
                    #pragma unroll
                    for (int ct2 = 0; ct2 < 4; ++ct2)
                        bR[nxt][ct2] = *(const bf16x8*)(&ft[bo + ct2 * 256]);
                }
                {   // A prefetch k+2 (2x global dwordx4, L2-resident)
                    const ushort_t* ap = abase + (kt2 + 2) * 8192;
                    aF[nxt][0] = *(const bf16x8*)(ap);
                    aF[nxt][1] = *(const bf16x8*)(ap + 512);
                }
            }

            // fold running colmax into this step's B (loaded 2 steps ago)
            bf16x8 bC[4];
            #pragma unroll
            for (int ct2 = 0; ct2 < 4; ++ct2) bC[ct2] = pkmax8(bR[cur][ct2], ml[ct2]);

            #pragma unroll
            for (int ct2 = 0; ct2 < 4; ++ct2) {
                acc[0][ct2] = __builtin_amdgcn_mfma_f32_32x32x16_bf16(
                    aF[cur][0], bC[ct2], acc[0][ct2], 0, 0, 0);
                acc[1][ct2] = __builtin_amdgcn_mfma_f32_32x32x16_bf16(
                    aF[cur][1], bC[ct2], acc[1][ct2], 0, 0, 0);
            }
        }

        // ---- colmax fold (D: col=lane&31; row identity irrelevant for colmax)
        #pragma unroll
        for (int ct2 = 0; ct2 < 4; ++ct2) {
            float m0 = -1e30f;
            #pragma unroll
            for (int rt2 = 0; rt2 < 2; ++rt2)
                #pragma unroll
                for (int e = 0; e < 16; ++e) m0 = fmaxf(m0, acc[rt2][ct2][e]);
            m0 = fmaxf(m0, __shfl_xor(m0, 32, 64));
            if (half == 0) wred[it & 1][wave][ct2 * 32 + l31] = m0;
        }

        // boundary reloads (slots 0,1 for next iteration's k=0,1): issue the
        // A loads before the barrier so L2 latency hides under it.
        if (it < n_iter - 1) {
            #pragma unroll
            for (int s = 0; s < 2; ++s) {
                aF[s][0] = *(const bf16x8*)(abase + s * 8192);
                aF[s][1] = *(const bf16x8*)(abase + s * 8192 + 512);
            }
        }
        __syncthreads();
        #pragma unroll
        for (int ct2 = 0; ct2 < 4; ++ct2) {
            const int c = ct2 * 32 + l31;
            float m = wred[it & 1][0][c];
            #pragma unroll
            for (int w = 1; w < WAVES; ++w) m = fmaxf(m, wred[it & 1][w][c]);
            mf[ct2] = fmaxf(mf[ct2], m);    // monotone guard vs bf16 wobble
            ml[ct2] = f2bf(mf[ct2]);
        }
        if (it < n_iter - 1) {
            #pragma unroll
            for (int s = 0; s < 2; ++s)
                #pragma unroll
                for (int ct2 = 0; ct2 < 4; ++ct2)
                    bR[s][ct2] = *(const bf16x8*)(&ft[bbase + s * 2048 + ct2 * 256]);
        }
        // wred double-buffered: next write to this buf is after the NEXT
        // iteration's barrier, beyond all reads above.
    }

    // ---- epilogue: out = max(ft, m_final); every thread recomputes m from
    // wred of the last iteration (already barriered). 1 col/lane, 256B
    // coalesced stores, conflict-free LDS reads.
    {
        const int c   = tid & 127;
        const int grp = tid >> 7;
        const int lb  = (n_iter > 0) ? ((n_iter - 1) & 1) : 0;
        float m = wred[lb][0][c];
        #pragma unroll
        for (int w = 1; w < WAVES; ++w) m = fmaxf(m, wred[lb][w][c]);
        #pragma unroll 4
        for (int s = 0; s < 16; ++s) {
            const int g = grp * 16 + s;
            ushort_t gb[8];
            *(int4*)gb = *(const int4*)(&ft[(g * NT + c) * 8]);
            #pragma unroll
            for (int i = 0; i < 8; ++i)
                out[(g * 8 + i) * CDIM + c0 + c] = fmaxf(bf2f(gb[i]), m);
        }
    }
}

extern "C" void kernel_launch(void* const* d_in, const int* in_sizes, int n_in,
                              void* d_out, int out_size, void* d_ws, size_t ws_size,
                              hipStream_t stream) {
    const float* facts    = (const float*)d_in[0];       // [512, 65536] fp32
    const float* rw       = (const float*)d_in[1];       // [512, 1, 512] fp32
    const int*   n_iter_p = (const int*)d_in[2];         // scalar 3
    float* out = (float*)d_out;

    ushort_t* Apk = (ushort_t*)d_ws;                     // 512 KB

    softmax_pack<<<PDIM, 64, 0, stream>>>(rw, Apk);
    ilp_kernel<<<CDIM / NT, 512, 0, stream>>>(facts, Apk, n_iter_p, out);
}

// Round 9
// 317.990 us; speedup vs baseline: 1.1610x; 1.1610x over previous
//
#include <hip/hip_runtime.h>
#include <hip/hip_bf16.h>
#include <cstdint>

// DifferentiableILP on MI355X (gfx950).
// A = softmax(rule_weights[:,0,:]); 3x: facts = max(facts, colmax(A @ facts)).
// Columns independent -> each block owns a 128-col stripe; ft immutable in LDS,
// running col-max folded into B fragments at use (packed u16 max).
//
// R11 changes vs R9 (ilp 156us) / R10 (spilled: FETCH 70->322MB, invalid test):
//  - Deep-pipeline theory retried WITHOUT spilling:
//    * A fragments 4-deep, slot = kt2 & 3 (power-of-2 -> static indices under
//      #pragma unroll 4; R10's %3 + full unroll caused dynamic ranges/spill).
//      Prefetch distance 3, issued post-cluster: ~3 k-steps (~1500cy) in
//      flight >> loaded-L2 latency; pre-cluster wait = vmcnt(6), 2-step slack.
//    * B stays 2-deep distance-2 (LDS ~120cy << wall; lgkmcnt(4) slack).
//  - Seamless cross-iteration pipeline: in-register fold keeps ft immutable;
//    kt2&3 is iteration-invariant at 32 steps, so wrap prefetches (kt2>=29)
//    land in the correct slots for the next iteration's k=0..2. No boundary
//    reloads (R10's register killer). Only the wred barrier (3x per kernel)
//    drains counters.
//  - Loop rolled (unroll 4); update pass deleted; rest identical to R9.

typedef __attribute__((ext_vector_type(8))) short bf16x8;   // 8 bf16 = 4 VGPRs
typedef __attribute__((ext_vector_type(8))) unsigned short u16x8;
typedef __attribute__((ext_vector_type(16))) float f32x16;  // 32x32 accumulator
typedef unsigned short ushort_t;
typedef unsigned int uint32;

#define PDIM 512
#define CDIM 65536
#define NT   128     // columns per block
#define WAVES 8

__device__ __forceinline__ ushort_t f2bf(float x) {          // RNE float->bf16
    uint32 u = __float_as_uint(x);
    return (ushort_t)((u + 0x7fffu + ((u >> 16) & 1u)) >> 16);
}
__device__ __forceinline__ float bf2f(uint32 bits) { return __uint_as_float(bits << 16); }

// packed max(v, splat(mu)) in the u16 domain (valid: all values are nonneg bf16)
__device__ __forceinline__ bf16x8 pkmax8(bf16x8 v, ushort_t mu) {
    u16x8 a = __builtin_bit_cast(u16x8, v);
    const u16x8 mb = {mu, mu, mu, mu, mu, mu, mu, mu};
    a = __builtin_elementwise_max(a, mb);
    return __builtin_bit_cast(bf16x8, a);
}

// ---- phase 1: softmax row r, packed fragment-linear for 32x32x16 MFMA.
// chunk idx16 = (kt2*16 + (r>>5))*64 + (ln&1)*32 + (r&31) holds
// A[r][kt2*16 + (ln&1)*8 .. +7] as 8 bf16.  (unchanged since R5)
__global__ __launch_bounds__(64) void softmax_pack(const float* __restrict__ rw,
                                                   ushort_t* __restrict__ Apk) {
    const int r  = blockIdx.x;
    const int ln = threadIdx.x;
    const float* row = rw + r * PDIM;
    float4 x0 = *(const float4*)(row + ln * 8);
    float4 x1 = *(const float4*)(row + ln * 8 + 4);
    float v[8] = {x0.x, x0.y, x0.z, x0.w, x1.x, x1.y, x1.z, x1.w};

    float mx = -1e30f;
    #pragma unroll
    for (int i = 0; i < 8; ++i) mx = fmaxf(mx, v[i]);
    #pragma unroll
    for (int d = 1; d < 64; d <<= 1) mx = fmaxf(mx, __shfl_xor(mx, d, 64));
    float s = 0.f;
    #pragma unroll
    for (int i = 0; i < 8; ++i) { v[i] = __expf(v[i] - mx); s += v[i]; }
    #pragma unroll
    for (int d = 1; d < 64; d <<= 1) s += __shfl_xor(s, d, 64);
    const float inv = 1.f / s;

    ushort_t o[8];
    #pragma unroll
    for (int i = 0; i < 8; ++i) o[i] = f2bf(v[i] * inv);
    const int idx16 = ((ln >> 1) * 16 + (r >> 5)) * 64 + ((ln & 1) << 5) + (r & 31);
    *(int4*)(Apk + idx16 * 8) = *(const int4*)o;
}

// ---- phase 2: per-128-column stripe, fused multi-iteration fixpoint.
// LDS ftB: 16B chunk (g, c) at element (g*NT + c)*8, g = p-granule (p=g*8..+7).
__global__ __launch_bounds__(512, 2) void ilp_kernel(
        const float* __restrict__ facts,
        const ushort_t* __restrict__ Apk,
        const int* __restrict__ n_iter_p,
        float* __restrict__ out) {
    __shared__ ushort_t ft[64 * NT * 8];   // 131072 B
    __shared__ float wred[2][WAVES][NT];   // 8192 B: per-wave colmax partials, dbuf

    const int tid  = threadIdx.x;
    const int wave = tid >> 6;
    const int lane = tid & 63;
    const int l31  = lane & 31;
    const int half = lane >> 5;
    const int c0   = blockIdx.x * NT;

    int n_iter = *n_iter_p;                // issue scalar load early
    n_iter = n_iter < 0 ? 0 : (n_iter > 8 ? 8 : n_iter);

    wred[0][wave][lane]      = 0.f;        // n_iter==0 safety
    wred[0][wave][lane + 64] = 0.f;

    // ---- stage: ftB[g][c] = bf16(facts[g*8..+7][c0+c]); 1 col/lane.
    // Global: 256B/wave-instr coalesced. LDS: 16 consecutive lanes span 256B
    // contiguous -> conflict-free b128 writes.
    {
        const int c   = tid & 127;
        const int grp = tid >> 7;          // 0..3
        #pragma unroll 4
        for (int s = 0; s < 16; ++s) {
            const int g = grp * 16 + s;
            ushort_t gb[8];
            #pragma unroll
            for (int i = 0; i < 8; ++i)
                gb[i] = f2bf(facts[(g * 8 + i) * CDIM + c0 + c]);
            *(int4*)(&ft[(g * NT + c) * 8]) = *(const int4*)gb;
        }
    }

    // A prologue (kt2=0,1,2 -> slots 0,1,2) issued before the barrier.
    // wave owns rows wave*64 + rt2*32 + l31;
    // element = wave*1024 + rt2*512 + (half*32+l31)*8 + kt2*8192.
    const ushort_t* abase = Apk + wave * 1024 + (half * 32 + l31) * 8;
    bf16x8 aF[4][2], bR[2][4];
    #pragma unroll
    for (int s = 0; s < 3; ++s) {
        aF[s][0] = *(const bf16x8*)(abase + s * 8192);
        aF[s][1] = *(const bf16x8*)(abase + s * 8192 + 512);
    }

    __syncthreads();

    // B element base: ((kt2*2+half)*NT + ct2*32 + l31)*8 = bbase + kt2*2048 + ct2*256
    const int bbase = (half * NT + l31) * 8;
    #pragma unroll
    for (int s = 0; s < 2; ++s)
        #pragma unroll
        for (int ct2 = 0; ct2 < 4; ++ct2)
            bR[s][ct2] = *(const bf16x8*)(&ft[bbase + s * 2048 + ct2 * 256]);

    ushort_t ml[4] = {0, 0, 0, 0};         // running colmax, bf16 bits
    float    mf[4] = {0.f, 0.f, 0.f, 0.f}; // running colmax, f32

    #pragma unroll 1
    for (int it = 0; it < n_iter; ++it) {
        f32x16 acc[2][4];
        #pragma unroll
        for (int rt2 = 0; rt2 < 2; ++rt2)
            #pragma unroll
            for (int ct2 = 0; ct2 < 4; ++ct2)
                #pragma unroll
                for (int e = 0; e < 16; ++e) acc[rt2][ct2][e] = 0.f;

        // ---- k-loop: rolled, unroll 4 (A slot kt2&3, B slot kt2&1 static).
        // Steady state: 6 A-loads + 4 B-reads outstanding -> pre-cluster
        // waits vmcnt(6)/lgkmcnt(4) are no-ops. Wrap prefetches (kt2>=29)
        // land in the correct slots for the next iteration (32&3==0).
        #pragma unroll 4
        for (int kt2 = 0; kt2 < 32; ++kt2) {
            const int a_cur = kt2 & 3;
            const int b_cur = kt2 & 1;

            // fold running colmax into this step's B (loaded 2 steps ago)
            bf16x8 bC[4];
            #pragma unroll
            for (int ct2 = 0; ct2 < 4; ++ct2)
                bC[ct2] = pkmax8(bR[b_cur][ct2], ml[ct2]);

            __builtin_amdgcn_s_setprio(1);
            #pragma unroll
            for (int ct2 = 0; ct2 < 4; ++ct2) {
                acc[0][ct2] = __builtin_amdgcn_mfma_f32_32x32x16_bf16(
                    aF[a_cur][0], bC[ct2], acc[0][ct2], 0, 0, 0);
                acc[1][ct2] = __builtin_amdgcn_mfma_f32_32x32x16_bf16(
                    aF[a_cur][1], bC[ct2], acc[1][ct2], 0, 0, 0);
            }
            __builtin_amdgcn_s_setprio(0);

            // post-cluster prefetches (different slots for A; B slot is the
            // one just consumed -> WAR-pinned after the cluster).
            {   // A distance-3 into slot (kt2+3)&3
                const ushort_t* ap = abase + ((kt2 + 3) & 31) * 8192;
                aF[(kt2 + 3) & 3][0] = *(const bf16x8*)(ap);
                aF[(kt2 + 3) & 3][1] = *(const bf16x8*)(ap + 512);
            }
            {   // B distance-2 into slot (kt2+2)&1 == b_cur
                const int bo = bbase + ((kt2 + 2) & 31) * 2048;
                #pragma unroll
                for (int ct2 = 0; ct2 < 4; ++ct2)
                    bR[b_cur][ct2] = *(const bf16x8*)(&ft[bo + ct2 * 256]);
            }
        }

        // ---- colmax fold (D: col=lane&31; row identity irrelevant for colmax)
        #pragma unroll
        for (int ct2 = 0; ct2 < 4; ++ct2) {
            float m0 = -1e30f;
            #pragma unroll
            for (int rt2 = 0; rt2 < 2; ++rt2)
                #pragma unroll
                for (int e = 0; e < 16; ++e) m0 = fmaxf(m0, acc[rt2][ct2][e]);
            m0 = fmaxf(m0, __shfl_xor(m0, 32, 64));
            if (half == 0) wred[it & 1][wave][ct2 * 32 + l31] = m0;
        }
        __syncthreads();
        #pragma unroll
        for (int ct2 = 0; ct2 < 4; ++ct2) {
            const int c = ct2 * 32 + l31;
            float m = wred[it & 1][0][c];
            #pragma unroll
            for (int w = 1; w < WAVES; ++w) m = fmaxf(m, wred[it & 1][w][c]);
            mf[ct2] = fmaxf(mf[ct2], m);    // monotone guard vs bf16 wobble
            ml[ct2] = f2bf(mf[ct2]);
        }
        // wred double-buffered: next write to this buf is after the NEXT
        // iteration's barrier, beyond all reads above. A/B pipeline slots
        // already hold next iteration's k=0..2 (wrap prefetches).
    }

    // ---- epilogue: out = max(ft, m_final); mf already holds the final
    // running colmax per ct2 -- but each thread needs m for its own column c,
    // so recompute from wred of the last iteration (already barriered).
    {
        const int c   = tid & 127;
        const int grp = tid >> 7;
        const int lb  = (n_iter > 0) ? ((n_iter - 1) & 1) : 0;
        float m = wred[lb][0][c];
        #pragma unroll
        for (int w = 1; w < WAVES; ++w) m = fmaxf(m, wred[lb][w][c]);
        #pragma unroll 4
        for (int s = 0; s < 16; ++s) {
            const int g = grp * 16 + s;
            ushort_t gb[8];
            *(int4*)gb = *(const int4*)(&ft[(g * NT + c) * 8]);
            #pragma unroll
            for (int i = 0; i < 8; ++i)
                out[(g * 8 + i) * CDIM + c0 + c] = fmaxf(bf2f(gb[i]), m);
        }
    }
}

extern "C" void kernel_launch(void* const* d_in, const int* in_sizes, int n_in,
                              void* d_out, int out_size, void* d_ws, size_t ws_size,
                              hipStream_t stream) {
    const float* facts    = (const float*)d_in[0];       // [512, 65536] fp32
    const float* rw       = (const float*)d_in[1];       // [512, 1, 512] fp32
    const int*   n_iter_p = (const int*)d_in[2];         // scalar 3
    float* out = (float*)d_out;

    ushort_t* Apk = (ushort_t*)d_ws;                     // 512 KB

    softmax_pack<<<PDIM, 64, 0, stream>>>(rw, Apk);
    ilp_kernel<<<CDIM / NT, 512, 0, stream>>>(facts, Apk, n_iter_p, out);
}